// Round 8
// baseline (168.215 us; speedup 1.0000x reference)
//
#include <hip/hip_runtime.h>
#include <hip/hip_bf16.h>
#include <math.h>

#define DMODEL 1024
#define NHEADS 16
#define DKH    64
#define BATCH  2
#define SEQ    2048
#define MROWS  (BATCH * SEQ)   // 4096
#define LOG2E  1.4426950408889634f

typedef __bf16 bf16_t;
typedef bf16_t bf16x8 __attribute__((ext_vector_type(8)));
typedef bf16_t bf16x4 __attribute__((ext_vector_type(4)));
typedef float  floatx4 __attribute__((ext_vector_type(4)));

// async global->LDS, 16B per lane
__device__ __forceinline__ void glds16(const bf16_t* g, bf16_t* l) {
    __builtin_amdgcn_global_load_lds((__attribute__((address_space(1))) unsigned*)(g),
                                     (__attribute__((address_space(3))) unsigned*)(l),
                                     16, 0, 0);
}

// ---------------------------------------------------------------- prep: cast x (z=0) + transpose W (z=1..4)
__global__ void prep_kernel(const float* __restrict__ x,
                            const float* __restrict__ W0, const float* __restrict__ W1,
                            const float* __restrict__ W2, const float* __restrict__ W3,
                            bf16_t* __restrict__ xb, bf16_t* __restrict__ Wt) {
    __shared__ float t[32][33];
    int bx = blockIdx.x, by = blockIdx.y, z = blockIdx.z;
    int tx = threadIdx.x, ty = threadIdx.y;
    if (z == 0) {   // cast x: 128 rows x 32 cols per block, float4-vectorized
        int tid = ty * 32 + tx;
#pragma unroll
        for (int k = 0; k < 4; ++k) {
            int slot = k * 256 + tid;            // 0..1023 float4 slots
            int row = by * 128 + (slot >> 3);
            int col = bx * 32 + (slot & 7) * 4;
            float4 v = *(const float4*)&x[(size_t)row * DMODEL + col];
            bf16x4 o = {(bf16_t)v.x, (bf16_t)v.y, (bf16_t)v.z, (bf16_t)v.w};
            *(bf16x4*)&xb[(size_t)row * DMODEL + col] = o;
        }
        return;
    }
    const float* W = (z == 1) ? W0 : (z == 2) ? W1 : (z == 3) ? W2 : W3;
    bf16_t* dst = Wt + (size_t)(z - 1) * DMODEL * DMODEL;
#pragma unroll
    for (int i = 0; i < 32; i += 8)
        t[ty + i][tx] = W[(size_t)(by * 32 + ty + i) * DMODEL + bx * 32 + tx];
    __syncthreads();
#pragma unroll
    for (int i = 0; i < 32; i += 8)
        dst[(size_t)(bx * 32 + ty + i) * DMODEL + by * 32 + tx] = (bf16_t)t[tx][ty + i];
}

// ---------------------------------------------------------------- fused QKV GEMM, 256x256, BK=64, 8-phase
// R3: 256^2 8-wave counted-vmcnt schedule (T2+T3+T4+T5). XCD swizzle reverted (R7:
// +3 us — L3-fit working set, matches m160 caveat).
__global__ __launch_bounds__(512) void gemm_qkv_kernel(const bf16_t* __restrict__ A,
                                                       const bf16_t* __restrict__ Bt,
                                                       bf16_t* __restrict__ Qfb,
                                                       bf16_t* __restrict__ Kfb,
                                                       bf16_t* __restrict__ Vfb) {
    extern __shared__ __align__(16) bf16_t sm[];   // 65536 bf16 = 128 KB
    int tid = threadIdx.x;
    int w = tid >> 6, l = tid & 63, g = l >> 4, lm = l & 15;
    int wr = w >> 2, wc = w & 3;            // 2M x 4N waves
    int m0 = blockIdx.y * 256, n0 = blockIdx.x * 256;

    int w8l3 = w * 8 + (l >> 3);
    int cw8  = ((l & 7) ^ (l >> 3)) * 8;
    const bf16_t* Ag0 = A  + (size_t)m0 * DMODEL;
    const bf16_t* Bg0 = Bt + (size_t)n0 * DMODEL;

#define STAGE(MATB, LDSB, hh, tt) do {                                             \
        const bf16_t* _src = (MATB) + (size_t)((hh) * 128 + w8l3) * DMODEL + (tt) * 64 + cw8; \
        bf16_t* _dst = (LDSB) + (hh) * 8192 + w * 8 * 64;                          \
        glds16(_src, _dst);                                                        \
        glds16(_src + (size_t)64 * DMODEL, _dst + 4096);                           \
    } while (0)

#define PH_SYNC() do { asm volatile("s_waitcnt vmcnt(4)" ::: "memory");            \
        __builtin_amdgcn_s_barrier(); __builtin_amdgcn_sched_barrier(0); } while (0)
#define PH_BAR() do { __builtin_amdgcn_s_barrier();                                \
        __builtin_amdgcn_sched_barrier(0); } while (0)

    floatx4 a00[4][2], a01[4][2], a10[4][2], a11[4][2];
#pragma unroll
    for (int i = 0; i < 4; ++i)
#pragma unroll
        for (int j = 0; j < 2; ++j) {
            floatx4 z = {0.f, 0.f, 0.f, 0.f};
            a00[i][j] = z; a01[i][j] = z; a10[i][j] = z; a11[i][j] = z;
        }
    bf16x8 af[4][2], bf0[2][2], bf1[2][2];

#define LOAD_AF(ihh, bb) do {                                                      \
        const bf16_t* _ab = sm + (bb) * 16384 + (ihh) * 8192;                      \
        _Pragma("unroll")                                                          \
        for (int i = 0; i < 4; ++i) {                                              \
            int _hr = (wr * 64 + i * 16 + lm) * 64;                                \
            af[i][0] = *(const bf16x8*)&_ab[_hr + ((g) ^ (lm & 7)) * 8];           \
            af[i][1] = *(const bf16x8*)&_ab[_hr + ((4 + g) ^ (lm & 7)) * 8];       \
        } } while (0)

#define LOAD_BF(BF, jhh, bb) do {                                                  \
        const bf16_t* _bb = sm + 32768 + (bb) * 16384 + (jhh) * 8192;              \
        _Pragma("unroll")                                                          \
        for (int j = 0; j < 2; ++j) {                                              \
            int _bc = (wc * 32 + j * 16 + lm) * 64;                                \
            BF[j][0] = *(const bf16x8*)&_bb[_bc + ((g) ^ (lm & 7)) * 8];           \
            BF[j][1] = *(const bf16x8*)&_bb[_bc + ((4 + g) ^ (lm & 7)) * 8];       \
        } } while (0)

#define MM(ACC, BF) do {                                                           \
        __builtin_amdgcn_s_setprio(1);                                             \
        _Pragma("unroll")                                                          \
        for (int kk = 0; kk < 2; ++kk)                                             \
        _Pragma("unroll")                                                          \
        for (int i = 0; i < 4; ++i)                                                \
        _Pragma("unroll")                                                          \
        for (int j = 0; j < 2; ++j)                                                \
            ACC[i][j] = __builtin_amdgcn_mfma_f32_16x16x32_bf16(af[i][kk], BF[j][kk], ACC[i][j], 0, 0, 0); \
        __builtin_amdgcn_s_setprio(0);                                             \
    } while (0)

    // prologue: stage tile 0 in consumption order [Ah0, Bh0, Bh1, Ah1]
    STAGE(Ag0, sm, 0, 0);
    STAGE(Bg0, sm + 32768, 0, 0);
    STAGE(Bg0, sm + 32768, 1, 0);
    STAGE(Ag0, sm, 1, 0);

    for (int t = 0; t < 16; ++t) {
        int buf = t & 1;
        bf16_t* An = sm + (buf ^ 1) * 16384;
        bf16_t* Bn = sm + 32768 + (buf ^ 1) * 16384;
        int tn = (t + 1) & 15;   // wrap-refetch keeps vmcnt counts uniform; harmless

        PH_SYNC();
        STAGE(Ag0, An, 0, tn);
        LOAD_AF(0, buf);
        LOAD_BF(bf0, 0, buf);
        MM(a00, bf0);
        PH_SYNC();
        STAGE(Bg0, Bn, 0, tn);
        LOAD_BF(bf1, 1, buf);
        MM(a01, bf1);
        PH_SYNC();
        STAGE(Bg0, Bn, 1, tn);
        LOAD_AF(1, buf);
        MM(a11, bf1);
        PH_BAR();
        STAGE(Ag0, An, 1, tn);
        MM(a10, bf0);
    }

    __syncthreads();   // full drain; LDS becomes the epilogue buffer
    int mat = blockIdx.x >> 2;              // 0=Q 1=K 2=V (4 col-blocks per matrix)
    int headb = (blockIdx.x & 3) * 4;
    int b = m0 >> 11;
    int ktb = (m0 & 2047) >> 6;
    const float scaleQ = 0.125f * LOG2E;

#define EPI(ACC, ihh, jhh)                                                          \
    _Pragma("unroll")                                                               \
    for (int i = 0; i < 4; ++i)                                                     \
    _Pragma("unroll")                                                               \
    for (int j = 0; j < 2; ++j) {                                                   \
        int s0_ = (ihh) * 128 + wr * 64 + i * 16 + g * 4;                           \
        int d_  = (jhh) * 128 + wc * 32 + j * 16 + lm;                              \
        int hc_ = d_ >> 6, d6 = d_ & 63, st_ = s0_ >> 6, s6 = s0_ & 63;             \
        int chunk = hc_ * 4 + st_;                                                  \
        if (mat == 0) {                                                             \
            int base = chunk * 4096 + ((s6 >> 4) * 2 + (d6 >> 5)) * 512 +           \
                       ((d6 >> 3) & 3) * 128 + (s6 & 15) * 8 + (d6 & 7);            \
            _Pragma("unroll")                                                       \
            for (int r = 0; r < 4; ++r)                                             \
                sm[base + r * 8] = (bf16_t)(ACC[i][j][r] * scaleQ);                 \
        } else if (mat == 1) {                                                      \
            int base = chunk * 4096 + (((s6 >> 5) & 1) * 4 + ((s6 >> 2) & 1) * 2 + (d6 >> 5)) * 512 + \
                       ((d6 >> 3) & 3) * 128 +                                      \
                       (((s6 >> 4) & 1) * 8 + ((s6 >> 3) & 1) * 4) * 8 + (d6 & 7);  \
            _Pragma("unroll")                                                       \
            for (int r = 0; r < 4; ++r)                                             \
                sm[base + r * 8] = (bf16_t)ACC[i][j][r];                            \
        } else {                                                                    \
            int base = chunk * 4096 + ((d6 >> 4) * 2 + ((s6 >> 5) & 1)) * 512 +     \
                       ((((s6 >> 4) & 1) * 2 + ((s6 >> 3) & 1)) * 16 + (d6 & 15)) * 8 + \
                       ((s6 >> 2) & 1) * 4;                                         \
            bf16x4 pk = {(bf16_t)ACC[i][j][0], (bf16_t)ACC[i][j][1],                \
                         (bf16_t)ACC[i][j][2], (bf16_t)ACC[i][j][3]};               \
            *(bf16x4*)&sm[base] = pk;                                               \
        }                                                                           \
    }

    EPI(a00, 0, 0);
    EPI(a01, 0, 1);
    EPI(a10, 1, 0);
    EPI(a11, 1, 1);

    __syncthreads();
    bf16_t* outbuf = (mat == 0) ? Qfb : (mat == 1) ? Kfb : Vfb;
#pragma unroll
    for (int rep = 0; rep < 16; ++rep) {
        int idx = rep * 512 + tid;
        int c = idx >> 9;                   // 16 chunks, 512 vec8 each
        int off = (idx & 511) * 8;
        int bh2 = b * NHEADS + headb + (c >> 2);
        int kt = ktb + (c & 3);
        *(bf16x8*)(outbuf + ((size_t)bh2 * 32 + kt) * 4096 + off) = *(const bf16x8*)&sm[c * 4096 + off];
    }
#undef STAGE
#undef PH_SYNC
#undef PH_BAR
#undef LOAD_AF
#undef LOAD_BF
#undef MM
#undef EPI
}

// ---------------------------------------------------------------- O-proj GEMM, 64x128 tile
// 64x128: grid 512 = 2 blk/CU — needed by the 2-barrier loop (128^2 @1 blk/CU
// measured +3 us, R4).
__global__ __launch_bounds__(256) void gemmO_kernel(const bf16_t* __restrict__ A,
                                                    const bf16_t* __restrict__ Bt,
                                                    float* __restrict__ outp) {
    __shared__ bf16_t As[64 * 64];
    __shared__ bf16_t Bs[128 * 64];
    int tid = threadIdx.x;
    int w = tid >> 6, l = tid & 63, g = l >> 4, lm = l & 15;
    int wr = w & 1, wc = w >> 1;
    int m0 = blockIdx.y * 64, n0 = blockIdx.x * 128;
    int r8 = l >> 3, s8 = l & 7, cw = s8 ^ r8;

    floatx4 acc[2][4];
#pragma unroll
    for (int i = 0; i < 2; ++i)
#pragma unroll
        for (int j = 0; j < 4; ++j) { floatx4 z = {0.f, 0.f, 0.f, 0.f}; acc[i][j] = z; }

    const bf16_t* Ag = A  + (size_t)(m0 + w * 16 + r8) * DMODEL + cw * 8;
    const bf16_t* Bg = Bt + (size_t)(n0 + w * 32 + r8) * DMODEL + cw * 8;

    for (int k0 = 0; k0 < DMODEL; k0 += 64) {
        __syncthreads();
#pragma unroll
        for (int j = 0; j < 2; ++j)
            glds16(Ag + (size_t)j * 8 * DMODEL + k0, &As[(w * 16 + j * 8) * 64]);
#pragma unroll
        for (int j = 0; j < 4; ++j)
            glds16(Bg + (size_t)j * 8 * DMODEL + k0, &Bs[(w * 32 + j * 8) * 64]);
        __syncthreads();
#pragma unroll
        for (int kk = 0; kk < 2; ++kk) {
            bf16x8 af[2], bfr[4];
            int c = kk * 4 + g;
            int sw = (c ^ (lm & 7)) * 8;
#pragma unroll
            for (int i = 0; i < 2; ++i)
                af[i] = *(const bf16x8*)&As[(wr * 32 + i * 16 + lm) * 64 + sw];
#pragma unroll
            for (int j = 0; j < 4; ++j)
                bfr[j] = *(const bf16x8*)&Bs[(wc * 64 + j * 16 + lm) * 64 + sw];
#pragma unroll
            for (int i = 0; i < 2; ++i)
#pragma unroll
                for (int j = 0; j < 4; ++j)
                    acc[i][j] = __builtin_amdgcn_mfma_f32_16x16x32_bf16(af[i], bfr[j], acc[i][j], 0, 0, 0);
        }
    }

#pragma unroll
    for (int i = 0; i < 2; ++i)
#pragma unroll
        for (int j = 0; j < 4; ++j) {
            int nc = n0 + wc * 64 + j * 16 + lm;
            int mb = m0 + wr * 32 + i * 16 + g * 4;
#pragma unroll
            for (int r = 0; r < 4; ++r)
                outp[(size_t)(mb + r) * DMODEL + nc] = acc[i][j][r];
        }
}

// ---------------------------------------------------------------- fused flash attention
// R8: R2-form loop (known-best warm) + GRID AXIS SWAP: (qb=blockIdx.x,
// bh=blockIdx.y). Same-bh blocks now have linear-ID stride 32 === 0 (mod 8 XCDs)
// -> all 32 q-blocks of one bh land on ONE XCD; each XCD holds 4 bh x 512 KB
// K/V = 2 MB < 4 MB L2 (was: bh fastest-varying -> every XCD touched all 32
// bh = 16 MB -> L2 thrash, K/V served from L3). Pure mapping change.
// LESSON (R4): no barriers in this loop. LESSON (R7): deeper K prefetch is
// neutral warm, worse cold — keep the R2-form interleave.
// DO NOT use (256,4): compiler caps VGPR at 64 and spills ~1.5 GB/launch.
__global__ __launch_bounds__(256, 2) void attn_kernel(const bf16_t* __restrict__ Qf,
                                                      const bf16_t* __restrict__ Kf,
                                                      const bf16_t* __restrict__ Vf,
                                                      bf16_t* __restrict__ Cc) {
    __shared__ __align__(16) char smem[24576];
    float*  Mbuf = (float*)smem;             // merge: [w][64*20], one 16-col chunk per phase
    float*  Lbuf = (float*)(smem + 20480);   // [w][64]
    bf16_t* Ct   = (bf16_t*)(smem + 21504);  // [w][16*24] store-assembly

    int tid = threadIdx.x;
    int w = tid >> 6, l = tid & 63, g = l >> 4, lm = l & 15;
    int bh = blockIdx.y, b = bh >> 4, h = bh & 15;   // R8: bh on Y
    int q0 = blockIdx.x * 64;                        // R8: q-block on X

    const bf16_t* Qfh = Qf + ((size_t)bh * 32 + (q0 >> 6)) * 4096 + l * 8;
    const bf16_t* Kfh = Kf + (size_t)bh * 32 * 4096 + l * 8;
    const bf16_t* Vfh = Vf + (size_t)bh * 32 * 4096 + l * 8;

    // Q B-frags: frag-major, 8 coalesced 1KB loads
    bf16x8 qf[4][2];
#pragma unroll
    for (int nt = 0; nt < 4; ++nt)
#pragma unroll
        for (int kk = 0; kk < 2; ++kk)
            qf[nt][kk] = *(const bf16x8*)(Qfh + (nt * 2 + kk) * 512);

    floatx4 oacc[4][4];
#pragma unroll
    for (int dt = 0; dt < 4; ++dt)
#pragma unroll
        for (int nt = 0; nt < 4; ++nt) { floatx4 z = {0.f, 0.f, 0.f, 0.f}; oacc[dt][nt] = z; }
    float lsum[4] = {0.f, 0.f, 0.f, 0.f};

    int kt0 = w * 8;
    bf16x8 kfa[2][2], kfb[2][2], vfa[4], vfb[4];
    {
        const bf16_t* Kb0 = Kfh + (size_t)kt0 * 4096;
#pragma unroll
        for (int c = 0; c < 2; ++c)
#pragma unroll
            for (int kk = 0; kk < 2; ++kk)
                kfa[c][kk] = *(const bf16x8*)(Kb0 + (c * 2 + kk) * 512);
    }

    for (int it = 0; it < 8; ++it) {
        const bf16_t* Tb = Kfh + (size_t)(kt0 + it) * 4096;
        const bf16_t* Vb = Vfh + (size_t)(kt0 + it) * 4096;
        const bf16_t* Tn = Kfh + (size_t)(kt0 + ((it < 7) ? it + 1 : 0)) * 4096;

        // loads: V half0, K half1
#pragma unroll
        for (int dt = 0; dt < 4; ++dt) vfa[dt] = *(const bf16x8*)(Vb + (dt * 2 + 0) * 512);
#pragma unroll
        for (int c = 0; c < 2; ++c)
#pragma unroll
            for (int kk = 0; kk < 2; ++kk)
                kfb[c][kk] = *(const bf16x8*)(Tb + (4 + c * 2 + kk) * 512);

        // S half0 (calls c=0,1 hold permuted key sets; slot j=c*4+r == key g*8+j)
        floatx4 sa[2][4];
#pragma unroll
        for (int c = 0; c < 2; ++c)
#pragma unroll
            for (int nt = 0; nt < 4; ++nt) { floatx4 z = {0.f, 0.f, 0.f, 0.f}; sa[c][nt] = z; }
        __builtin_amdgcn_s_setprio(1);
#pragma unroll
        for (int kk = 0; kk < 2; ++kk)
#pragma unroll
            for (int c = 0; c < 2; ++c)
#pragma unroll
                for (int nt = 0; nt < 4; ++nt)
                    sa[c][nt] = __builtin_amdgcn_mfma_f32_16x16x32_bf16(kfa[c][kk], qf[nt][kk], sa[c][nt], 0, 0, 0);
        __builtin_amdgcn_s_setprio(0);

        // loads: V half1, K half0 of next tile
#pragma unroll
        for (int dt = 0; dt < 4; ++dt) vfb[dt] = *(const bf16x8*)(Vb + (dt * 2 + 1) * 512);
#pragma unroll
        for (int c = 0; c < 2; ++c)
#pragma unroll
            for (int kk = 0; kk < 2; ++kk)
                kfa[c][kk] = *(const bf16x8*)(Tn + (c * 2 + kk) * 512);

        // S half1 — independent of exp(half0)
        floatx4 sb[2][4];
#pragma unroll
        for (int c = 0; c < 2; ++c)
#pragma unroll
            for (int nt = 0; nt < 4; ++nt) { floatx4 z = {0.f, 0.f, 0.f, 0.f}; sb[c][nt] = z; }
        __builtin_amdgcn_s_setprio(1);
#pragma unroll
        for (int kk = 0; kk < 2; ++kk)
#pragma unroll
            for (int c = 0; c < 2; ++c)
#pragma unroll
                for (int nt = 0; nt < 4; ++nt)
                    sb[c][nt] = __builtin_amdgcn_mfma_f32_16x16x32_bf16(kfb[c][kk], qf[nt][kk], sb[c][nt], 0, 0, 0);
        __builtin_amdgcn_s_setprio(0);

        // --- half0: exp + in-register pack + PV (no LDS) ---
        {
            bf16x8 bp[4];
#pragma unroll
            for (int nt = 0; nt < 4; ++nt) {
                float p0 = __builtin_amdgcn_exp2f(sa[0][nt][0]);
                float p1 = __builtin_amdgcn_exp2f(sa[0][nt][1]);
                float p2 = __builtin_amdgcn_exp2f(sa[0][nt][2]);
                float p3 = __builtin_amdgcn_exp2f(sa[0][nt][3]);
                float p4 = __builtin_amdgcn_exp2f(sa[1][nt][0]);
                float p5 = __builtin_amdgcn_exp2f(sa[1][nt][1]);
                float p6 = __builtin_amdgcn_exp2f(sa[1][nt][2]);
                float p7 = __builtin_amdgcn_exp2f(sa[1][nt][3]);
                lsum[nt] += ((p0 + p1) + (p2 + p3)) + ((p4 + p5) + (p6 + p7));
                bf16x8 pk = {(bf16_t)p0, (bf16_t)p1, (bf16_t)p2, (bf16_t)p3,
                             (bf16_t)p4, (bf16_t)p5, (bf16_t)p6, (bf16_t)p7};
                bp[nt] = pk;
            }
            __builtin_amdgcn_s_setprio(1);
#pragma unroll
            for (int dt = 0; dt < 4; ++dt)
#pragma unroll
                for (int nt = 0; nt < 4; ++nt)
                    oacc[dt][nt] = __builtin_amdgcn_mfma_f32_16x16x32_bf16(vfa[dt], bp[nt], oacc[dt][nt], 0, 0, 0);
            __builtin_amdgcn_s_setprio(0);
        }

        // --- half1: exp + in-register pack + PV (no LDS) ---
        {
            bf16x8 bp[4];
#pragma unroll
            for (int nt = 0; nt < 4; ++nt) {
                float p0 = __builtin_amdgcn_exp2f(sb[0][nt][0]);
                float p1 = __builtin_amdgcn_exp2f(sb[0][nt][1]);
                float p2 = __builtin_amdgcn_exp2f(sb[0][nt][2]);
                float p3 = __builtin_amdgcn_exp2f(sb[0][nt][3]);
                float p4 = __builtin_amdgcn_exp2f(sb[1][nt][0]);
                float p5 = __builtin_amdgcn_exp2f(sb[1][nt][1]);
                float p6 = __builtin_amdgcn_exp2f(sb[1][nt][2]);
                float p7 = __builtin_amdgcn_exp2f(sb[1][nt][3]);
                lsum[nt] += ((p0 + p1) + (p2 + p3)) + ((p4 + p5) + (p6 + p7));
                bf16x8 pk = {(bf16_t)p0, (bf16_t)p1, (bf16_t)p2, (bf16_t)p3,
                             (bf16_t)p4, (bf16_t)p5, (bf16_t)p6, (bf16_t)p7};
                bp[nt] = pk;
            }
            __builtin_amdgcn_s_setprio(1);
#pragma unroll
            for (int dt = 0; dt < 4; ++dt)
#pragma unroll
                for (int nt = 0; nt < 4; ++nt)
                    oacc[dt][nt] = __builtin_amdgcn_mfma_f32_16x16x32_bf16(vfb[dt], bp[nt], oacc[dt][nt], 0, 0, 0);
            __builtin_amdgcn_s_setprio(0);
        }
    }

    // reduce lsum within wave across g-groups
#pragma unroll
    for (int nt = 0; nt < 4; ++nt) {
        float s = lsum[nt];
        s += __shfl_xor(s, 16, 64);
        s += __shfl_xor(s, 32, 64);
        lsum[nt] = s;
    }

    // 4-partial merge through LDS, 4 phases (one 16-col d-chunk each, keeps LDS at 24 KB)
    float linv = 0.f;
#pragma unroll
    for (int p = 0; p < 4; ++p) {
        __syncthreads();
#pragma unroll
        for (int nt = 0; nt < 4; ++nt)
            *(floatx4*)&Mbuf[w * 1280 + (nt * 16 + lm) * 20 + g * 4] = oacc[p][nt];
        if (p == 0 && g == 0)
#pragma unroll
            for (int nt = 0; nt < 4; ++nt)
                Lbuf[w * 64 + nt * 16 + lm] = lsum[nt];
        __syncthreads();
        if (p == 0) {
            float lt = 0.f;
#pragma unroll
            for (int w2 = 0; w2 < 4; ++w2)
                lt += Lbuf[w2 * 64 + w * 16 + lm];
            linv = 1.0f / lt;
        }
        {
            floatx4 s = {0.f, 0.f, 0.f, 0.f};
#pragma unroll
            for (int w2 = 0; w2 < 4; ++w2)
                s += *(const floatx4*)&Mbuf[w2 * 1280 + (w * 16 + lm) * 20 + g * 4];
            bf16x4 pk = {(bf16_t)(s[0] * linv), (bf16_t)(s[1] * linv),
                         (bf16_t)(s[2] * linv), (bf16_t)(s[3] * linv)};
            *(bf16x4*)&Ct[w * 384 + lm * 24 + g * 4] = pk;
        }
        // cooperative row store: 8B/lane, 32B per row
        {
            int row = l >> 2, dp = l & 3;
            bf16x4 v = *(const bf16x4*)&Ct[w * 384 + row * 24 + dp * 4];
            *(bf16x4*)&Cc[((size_t)(b * SEQ + q0 + w * 16 + row)) * DMODEL + h * DKH + p * 16 + dp * 4] = v;
        }
    }
}

// ----------------------------------------------------------------------------
extern "C" void kernel_launch(void* const* d_in, const int* in_sizes, int n_in,
                              void* d_out, int out_size, void* d_ws, size_t ws_size,
                              hipStream_t stream) {
    const float* x  = (const float*)d_in[0];
    const float* Wq = (const float*)d_in[1];
    const float* Wk = (const float*)d_in[2];
    const float* Wv = (const float*)d_in[3];
    const float* Wo = (const float*)d_in[4];

    const size_t NX = (size_t)MROWS * DMODEL;
    const size_t NW = (size_t)DMODEL * DMODEL;
    bf16_t* ws  = (bf16_t*)d_ws;
    bf16_t* xb  = ws;            // x bf16
    bf16_t* Wt  = xb + NX;       // W^T x4 contiguous: q,k,v,o
    bf16_t* Wto = Wt + 3 * NW;
    bf16_t* Qfb = Wt + 4 * NW;   // Q frag-major (B-operand), scaled log2(e)/8
    bf16_t* Kfb = Qfb + NX;      // K frag-major (key-permuted A-operand)
    bf16_t* Vfb = Kfb + NX;      // V frag-major
    bf16_t* Cc  = Vfb + NX;      // concat

    prep_kernel<<<dim3(32, 32, 5), dim3(32, 8), 0, stream>>>(x, Wq, Wk, Wv, Wo, xb, Wt);

    gemm_qkv_kernel<<<dim3(12, 16), 512, 131072, stream>>>(xb, Wt, Qfb, Kfb, Vfb);

    // R8: q-block on X, bh on Y — same-bh blocks co-locate on one XCD's L2
    attn_kernel<<<dim3(SEQ / 64, BATCH * NHEADS), 256, 0, stream>>>(Qfb, Kfb, Vfb, Cc);

    gemmO_kernel<<<dim3(DMODEL / 128, MROWS / 64), 256, 0, stream>>>(Cc, Wto, (float*)d_out);
}

// Round 9
// 164.476 us; speedup vs baseline: 1.0227x; 1.0227x over previous
//
#include <hip/hip_runtime.h>
#include <hip/hip_bf16.h>
#include <math.h>

#define DMODEL 1024
#define NHEADS 16
#define DKH    64
#define BATCH  2
#define SEQ    2048
#define MROWS  (BATCH * SEQ)   // 4096
#define LOG2E  1.4426950408889634f

typedef __bf16 bf16_t;
typedef bf16_t bf16x8 __attribute__((ext_vector_type(8)));
typedef bf16_t bf16x4 __attribute__((ext_vector_type(4)));
typedef float  floatx4 __attribute__((ext_vector_type(4)));

// async global->LDS, 16B per lane
__device__ __forceinline__ void glds16(const bf16_t* g, bf16_t* l) {
    __builtin_amdgcn_global_load_lds((__attribute__((address_space(1))) unsigned*)(g),
                                     (__attribute__((address_space(3))) unsigned*)(l),
                                     16, 0, 0);
}

// ---------------------------------------------------------------- prep: cast x (z=0) + transpose W (z=1..4)
__global__ void prep_kernel(const float* __restrict__ x,
                            const float* __restrict__ W0, const float* __restrict__ W1,
                            const float* __restrict__ W2, const float* __restrict__ W3,
                            bf16_t* __restrict__ xb, bf16_t* __restrict__ Wt) {
    __shared__ float t[32][33];
    int bx = blockIdx.x, by = blockIdx.y, z = blockIdx.z;
    int tx = threadIdx.x, ty = threadIdx.y;
    if (z == 0) {   // cast x: 128 rows x 32 cols per block, float4-vectorized
        int tid = ty * 32 + tx;
#pragma unroll
        for (int k = 0; k < 4; ++k) {
            int slot = k * 256 + tid;            // 0..1023 float4 slots
            int row = by * 128 + (slot >> 3);
            int col = bx * 32 + (slot & 7) * 4;
            float4 v = *(const float4*)&x[(size_t)row * DMODEL + col];
            bf16x4 o = {(bf16_t)v.x, (bf16_t)v.y, (bf16_t)v.z, (bf16_t)v.w};
            *(bf16x4*)&xb[(size_t)row * DMODEL + col] = o;
        }
        return;
    }
    const float* W = (z == 1) ? W0 : (z == 2) ? W1 : (z == 3) ? W2 : W3;
    bf16_t* dst = Wt + (size_t)(z - 1) * DMODEL * DMODEL;
#pragma unroll
    for (int i = 0; i < 32; i += 8)
        t[ty + i][tx] = W[(size_t)(by * 32 + ty + i) * DMODEL + bx * 32 + tx];
    __syncthreads();
#pragma unroll
    for (int i = 0; i < 32; i += 8)
        dst[(size_t)(bx * 32 + ty + i) * DMODEL + by * 32 + tx] = (bf16_t)t[tx][ty + i];
}

// ---------------------------------------------------------------- fused QKV GEMM, 256x256, BK=64, 8-phase
// R3: 256^2 8-wave counted-vmcnt schedule (T2+T3+T4+T5). XCD swizzle reverted (R7:
// +3 us — L3-fit working set, matches m160 caveat).
__global__ __launch_bounds__(512) void gemm_qkv_kernel(const bf16_t* __restrict__ A,
                                                       const bf16_t* __restrict__ Bt,
                                                       bf16_t* __restrict__ Qfb,
                                                       bf16_t* __restrict__ Kfb,
                                                       bf16_t* __restrict__ Vfb) {
    extern __shared__ __align__(16) bf16_t sm[];   // 65536 bf16 = 128 KB
    int tid = threadIdx.x;
    int w = tid >> 6, l = tid & 63, g = l >> 4, lm = l & 15;
    int wr = w >> 2, wc = w & 3;            // 2M x 4N waves
    int m0 = blockIdx.y * 256, n0 = blockIdx.x * 256;

    int w8l3 = w * 8 + (l >> 3);
    int cw8  = ((l & 7) ^ (l >> 3)) * 8;
    const bf16_t* Ag0 = A  + (size_t)m0 * DMODEL;
    const bf16_t* Bg0 = Bt + (size_t)n0 * DMODEL;

#define STAGE(MATB, LDSB, hh, tt) do {                                             \
        const bf16_t* _src = (MATB) + (size_t)((hh) * 128 + w8l3) * DMODEL + (tt) * 64 + cw8; \
        bf16_t* _dst = (LDSB) + (hh) * 8192 + w * 8 * 64;                          \
        glds16(_src, _dst);                                                        \
        glds16(_src + (size_t)64 * DMODEL, _dst + 4096);                           \
    } while (0)

#define PH_SYNC() do { asm volatile("s_waitcnt vmcnt(4)" ::: "memory");            \
        __builtin_amdgcn_s_barrier(); __builtin_amdgcn_sched_barrier(0); } while (0)
#define PH_BAR() do { __builtin_amdgcn_s_barrier();                                \
        __builtin_amdgcn_sched_barrier(0); } while (0)

    floatx4 a00[4][2], a01[4][2], a10[4][2], a11[4][2];
#pragma unroll
    for (int i = 0; i < 4; ++i)
#pragma unroll
        for (int j = 0; j < 2; ++j) {
            floatx4 z = {0.f, 0.f, 0.f, 0.f};
            a00[i][j] = z; a01[i][j] = z; a10[i][j] = z; a11[i][j] = z;
        }
    bf16x8 af[4][2], bf0[2][2], bf1[2][2];

#define LOAD_AF(ihh, bb) do {                                                      \
        const bf16_t* _ab = sm + (bb) * 16384 + (ihh) * 8192;                      \
        _Pragma("unroll")                                                          \
        for (int i = 0; i < 4; ++i) {                                              \
            int _hr = (wr * 64 + i * 16 + lm) * 64;                                \
            af[i][0] = *(const bf16x8*)&_ab[_hr + ((g) ^ (lm & 7)) * 8];           \
            af[i][1] = *(const bf16x8*)&_ab[_hr + ((4 + g) ^ (lm & 7)) * 8];       \
        } } while (0)

#define LOAD_BF(BF, jhh, bb) do {                                                  \
        const bf16_t* _bb = sm + 32768 + (bb) * 16384 + (jhh) * 8192;              \
        _Pragma("unroll")                                                          \
        for (int j = 0; j < 2; ++j) {                                              \
            int _bc = (wc * 32 + j * 16 + lm) * 64;                                \
            BF[j][0] = *(const bf16x8*)&_bb[_bc + ((g) ^ (lm & 7)) * 8];           \
            BF[j][1] = *(const bf16x8*)&_bb[_bc + ((4 + g) ^ (lm & 7)) * 8];       \
        } } while (0)

#define MM(ACC, BF) do {                                                           \
        __builtin_amdgcn_s_setprio(1);                                             \
        _Pragma("unroll")                                                          \
        for (int kk = 0; kk < 2; ++kk)                                             \
        _Pragma("unroll")                                                          \
        for (int i = 0; i < 4; ++i)                                                \
        _Pragma("unroll")                                                          \
        for (int j = 0; j < 2; ++j)                                                \
            ACC[i][j] = __builtin_amdgcn_mfma_f32_16x16x32_bf16(af[i][kk], BF[j][kk], ACC[i][j], 0, 0, 0); \
        __builtin_amdgcn_s_setprio(0);                                             \
    } while (0)

    // prologue: stage tile 0 in consumption order [Ah0, Bh0, Bh1, Ah1]
    STAGE(Ag0, sm, 0, 0);
    STAGE(Bg0, sm + 32768, 0, 0);
    STAGE(Bg0, sm + 32768, 1, 0);
    STAGE(Ag0, sm, 1, 0);

    for (int t = 0; t < 16; ++t) {
        int buf = t & 1;
        bf16_t* An = sm + (buf ^ 1) * 16384;
        bf16_t* Bn = sm + 32768 + (buf ^ 1) * 16384;
        int tn = (t + 1) & 15;   // wrap-refetch keeps vmcnt counts uniform; harmless

        PH_SYNC();
        STAGE(Ag0, An, 0, tn);
        LOAD_AF(0, buf);
        LOAD_BF(bf0, 0, buf);
        MM(a00, bf0);
        PH_SYNC();
        STAGE(Bg0, Bn, 0, tn);
        LOAD_BF(bf1, 1, buf);
        MM(a01, bf1);
        PH_SYNC();
        STAGE(Bg0, Bn, 1, tn);
        LOAD_AF(1, buf);
        MM(a11, bf1);
        PH_BAR();
        STAGE(Ag0, An, 1, tn);
        MM(a10, bf0);
    }

    __syncthreads();   // full drain; LDS becomes the epilogue buffer
    int mat = blockIdx.x >> 2;              // 0=Q 1=K 2=V (4 col-blocks per matrix)
    int headb = (blockIdx.x & 3) * 4;
    int b = m0 >> 11;
    int ktb = (m0 & 2047) >> 6;
    const float scaleQ = 0.125f * LOG2E;

#define EPI(ACC, ihh, jhh)                                                          \
    _Pragma("unroll")                                                               \
    for (int i = 0; i < 4; ++i)                                                     \
    _Pragma("unroll")                                                               \
    for (int j = 0; j < 2; ++j) {                                                   \
        int s0_ = (ihh) * 128 + wr * 64 + i * 16 + g * 4;                           \
        int d_  = (jhh) * 128 + wc * 32 + j * 16 + lm;                              \
        int hc_ = d_ >> 6, d6 = d_ & 63, st_ = s0_ >> 6, s6 = s0_ & 63;             \
        int chunk = hc_ * 4 + st_;                                                  \
        if (mat == 0) {                                                             \
            int base = chunk * 4096 + ((s6 >> 4) * 2 + (d6 >> 5)) * 512 +           \
                       ((d6 >> 3) & 3) * 128 + (s6 & 15) * 8 + (d6 & 7);            \
            _Pragma("unroll")                                                       \
            for (int r = 0; r < 4; ++r)                                             \
                sm[base + r * 8] = (bf16_t)(ACC[i][j][r] * scaleQ);                 \
        } else if (mat == 1) {                                                      \
            int base = chunk * 4096 + (((s6 >> 5) & 1) * 4 + ((s6 >> 2) & 1) * 2 + (d6 >> 5)) * 512 + \
                       ((d6 >> 3) & 3) * 128 +                                      \
                       (((s6 >> 4) & 1) * 8 + ((s6 >> 3) & 1) * 4) * 8 + (d6 & 7);  \
            _Pragma("unroll")                                                       \
            for (int r = 0; r < 4; ++r)                                             \
                sm[base + r * 8] = (bf16_t)ACC[i][j][r];                            \
        } else {                                                                    \
            int base = chunk * 4096 + ((d6 >> 4) * 2 + ((s6 >> 5) & 1)) * 512 +     \
                       ((((s6 >> 4) & 1) * 2 + ((s6 >> 3) & 1)) * 16 + (d6 & 15)) * 8 + \
                       ((s6 >> 2) & 1) * 4;                                         \
            bf16x4 pk = {(bf16_t)ACC[i][j][0], (bf16_t)ACC[i][j][1],                \
                         (bf16_t)ACC[i][j][2], (bf16_t)ACC[i][j][3]};               \
            *(bf16x4*)&sm[base] = pk;                                               \
        }                                                                           \
    }

    EPI(a00, 0, 0);
    EPI(a01, 0, 1);
    EPI(a10, 1, 0);
    EPI(a11, 1, 1);

    __syncthreads();
    bf16_t* outbuf = (mat == 0) ? Qfb : (mat == 1) ? Kfb : Vfb;
#pragma unroll
    for (int rep = 0; rep < 16; ++rep) {
        int idx = rep * 512 + tid;
        int c = idx >> 9;                   // 16 chunks, 512 vec8 each
        int off = (idx & 511) * 8;
        int bh2 = b * NHEADS + headb + (c >> 2);
        int kt = ktb + (c & 3);
        *(bf16x8*)(outbuf + ((size_t)bh2 * 32 + kt) * 4096 + off) = *(const bf16x8*)&sm[c * 4096 + off];
    }
#undef STAGE
#undef PH_SYNC
#undef PH_BAR
#undef LOAD_AF
#undef LOAD_BF
#undef MM
#undef EPI
}

// ---------------------------------------------------------------- O-proj GEMM, 64x128 tile
// 64x128: grid 512 = 2 blk/CU — needed by the 2-barrier loop (128^2 @1 blk/CU
// measured +3 us, R4).
__global__ __launch_bounds__(256) void gemmO_kernel(const bf16_t* __restrict__ A,
                                                    const bf16_t* __restrict__ Bt,
                                                    float* __restrict__ outp) {
    __shared__ bf16_t As[64 * 64];
    __shared__ bf16_t Bs[128 * 64];
    int tid = threadIdx.x;
    int w = tid >> 6, l = tid & 63, g = l >> 4, lm = l & 15;
    int wr = w & 1, wc = w >> 1;
    int m0 = blockIdx.y * 64, n0 = blockIdx.x * 128;
    int r8 = l >> 3, s8 = l & 7, cw = s8 ^ r8;

    floatx4 acc[2][4];
#pragma unroll
    for (int i = 0; i < 2; ++i)
#pragma unroll
        for (int j = 0; j < 4; ++j) { floatx4 z = {0.f, 0.f, 0.f, 0.f}; acc[i][j] = z; }

    const bf16_t* Ag = A  + (size_t)(m0 + w * 16 + r8) * DMODEL + cw * 8;
    const bf16_t* Bg = Bt + (size_t)(n0 + w * 32 + r8) * DMODEL + cw * 8;

    for (int k0 = 0; k0 < DMODEL; k0 += 64) {
        __syncthreads();
#pragma unroll
        for (int j = 0; j < 2; ++j)
            glds16(Ag + (size_t)j * 8 * DMODEL + k0, &As[(w * 16 + j * 8) * 64]);
#pragma unroll
        for (int j = 0; j < 4; ++j)
            glds16(Bg + (size_t)j * 8 * DMODEL + k0, &Bs[(w * 32 + j * 8) * 64]);
        __syncthreads();
#pragma unroll
        for (int kk = 0; kk < 2; ++kk) {
            bf16x8 af[2], bfr[4];
            int c = kk * 4 + g;
            int sw = (c ^ (lm & 7)) * 8;
#pragma unroll
            for (int i = 0; i < 2; ++i)
                af[i] = *(const bf16x8*)&As[(wr * 32 + i * 16 + lm) * 64 + sw];
#pragma unroll
            for (int j = 0; j < 4; ++j)
                bfr[j] = *(const bf16x8*)&Bs[(wc * 64 + j * 16 + lm) * 64 + sw];
#pragma unroll
            for (int i = 0; i < 2; ++i)
#pragma unroll
                for (int j = 0; j < 4; ++j)
                    acc[i][j] = __builtin_amdgcn_mfma_f32_16x16x32_bf16(af[i], bfr[j], acc[i][j], 0, 0, 0);
        }
    }

#pragma unroll
    for (int i = 0; i < 2; ++i)
#pragma unroll
        for (int j = 0; j < 4; ++j) {
            int nc = n0 + wc * 64 + j * 16 + lm;
            int mb = m0 + wr * 32 + i * 16 + g * 4;
#pragma unroll
            for (int r = 0; r < 4; ++r)
                outp[(size_t)(mb + r) * DMODEL + nc] = acc[i][j][r];
        }
}

// ---------------------------------------------------------------- fused flash attention
// R9: R3 grid mapping restored (bh on X: same-bh q-blocks have linear-ID stride
// 32 === 0 mod 8 -> already co-located per XCD; R8's swap scattered them, +2.3 us).
// R2-form barrier-free loop. K frags key-permuted at production so QK^T output IS
// the PV B-operand — P stays in registers.
// R9 NEW: lsum via MFMA ones-trick — lacc[nt] = mfma(ones, bp[nt], lacc[nt]):
// the k-reduction sums P over the half's 32 keys on the matrix pipe, replacing
// 448 serial VALU adds/wave + the 2-shfl cross-g reduce (every lane ends holding
// the full per-q sum for this wave's keys; C/D rows identical).
// LESSON (R4): no barriers in this loop. LESSON (R7): deeper K prefetch neutral
// warm, worse cold. DO NOT use (256,4): VGPR cap 64 -> ~1.5 GB spills.
__global__ __launch_bounds__(256, 2) void attn_kernel(const bf16_t* __restrict__ Qf,
                                                      const bf16_t* __restrict__ Kf,
                                                      const bf16_t* __restrict__ Vf,
                                                      bf16_t* __restrict__ Cc) {
    __shared__ __align__(16) char smem[24576];
    float*  Mbuf = (float*)smem;             // merge: [w][64*20], one 16-col chunk per phase
    float*  Lbuf = (float*)(smem + 20480);   // [w][64]
    bf16_t* Ct   = (bf16_t*)(smem + 21504);  // [w][16*24] store-assembly

    int tid = threadIdx.x;
    int w = tid >> 6, l = tid & 63, g = l >> 4, lm = l & 15;
    int bh = blockIdx.x, b = bh >> 4, h = bh & 15;
    int q0 = blockIdx.y * 64;

    const bf16_t* Qfh = Qf + ((size_t)bh * 32 + (q0 >> 6)) * 4096 + l * 8;
    const bf16_t* Kfh = Kf + (size_t)bh * 32 * 4096 + l * 8;
    const bf16_t* Vfh = Vf + (size_t)bh * 32 * 4096 + l * 8;

    // Q B-frags: frag-major, 8 coalesced 1KB loads
    bf16x8 qf[4][2];
#pragma unroll
    for (int nt = 0; nt < 4; ++nt)
#pragma unroll
        for (int kk = 0; kk < 2; ++kk)
            qf[nt][kk] = *(const bf16x8*)(Qfh + (nt * 2 + kk) * 512);

    floatx4 oacc[4][4];
#pragma unroll
    for (int dt = 0; dt < 4; ++dt)
#pragma unroll
        for (int nt = 0; nt < 4; ++nt) { floatx4 z = {0.f, 0.f, 0.f, 0.f}; oacc[dt][nt] = z; }
    floatx4 lacc[4];
#pragma unroll
    for (int nt = 0; nt < 4; ++nt) { floatx4 z = {0.f, 0.f, 0.f, 0.f}; lacc[nt] = z; }
    bf16x8 vone;
#pragma unroll
    for (int j = 0; j < 8; ++j) vone[j] = (bf16_t)1.0f;

    int kt0 = w * 8;
    bf16x8 kfa[2][2], kfb[2][2], vfa[4], vfb[4];
    {
        const bf16_t* Kb0 = Kfh + (size_t)kt0 * 4096;
#pragma unroll
        for (int c = 0; c < 2; ++c)
#pragma unroll
            for (int kk = 0; kk < 2; ++kk)
                kfa[c][kk] = *(const bf16x8*)(Kb0 + (c * 2 + kk) * 512);
    }

    for (int it = 0; it < 8; ++it) {
        const bf16_t* Tb = Kfh + (size_t)(kt0 + it) * 4096;
        const bf16_t* Vb = Vfh + (size_t)(kt0 + it) * 4096;
        const bf16_t* Tn = Kfh + (size_t)(kt0 + ((it < 7) ? it + 1 : 0)) * 4096;

        // loads: V half0, K half1
#pragma unroll
        for (int dt = 0; dt < 4; ++dt) vfa[dt] = *(const bf16x8*)(Vb + (dt * 2 + 0) * 512);
#pragma unroll
        for (int c = 0; c < 2; ++c)
#pragma unroll
            for (int kk = 0; kk < 2; ++kk)
                kfb[c][kk] = *(const bf16x8*)(Tb + (4 + c * 2 + kk) * 512);

        // S half0 (calls c=0,1 hold permuted key sets; slot j=c*4+r == key g*8+j)
        floatx4 sa[2][4];
#pragma unroll
        for (int c = 0; c < 2; ++c)
#pragma unroll
            for (int nt = 0; nt < 4; ++nt) { floatx4 z = {0.f, 0.f, 0.f, 0.f}; sa[c][nt] = z; }
        __builtin_amdgcn_s_setprio(1);
#pragma unroll
        for (int kk = 0; kk < 2; ++kk)
#pragma unroll
            for (int c = 0; c < 2; ++c)
#pragma unroll
                for (int nt = 0; nt < 4; ++nt)
                    sa[c][nt] = __builtin_amdgcn_mfma_f32_16x16x32_bf16(kfa[c][kk], qf[nt][kk], sa[c][nt], 0, 0, 0);
        __builtin_amdgcn_s_setprio(0);

        // loads: V half1, K half0 of next tile
#pragma unroll
        for (int dt = 0; dt < 4; ++dt) vfb[dt] = *(const bf16x8*)(Vb + (dt * 2 + 1) * 512);
#pragma unroll
        for (int c = 0; c < 2; ++c)
#pragma unroll
            for (int kk = 0; kk < 2; ++kk)
                kfa[c][kk] = *(const bf16x8*)(Tn + (c * 2 + kk) * 512);

        // S half1 — independent of exp(half0)
        floatx4 sb[2][4];
#pragma unroll
        for (int c = 0; c < 2; ++c)
#pragma unroll
            for (int nt = 0; nt < 4; ++nt) { floatx4 z = {0.f, 0.f, 0.f, 0.f}; sb[c][nt] = z; }
        __builtin_amdgcn_s_setprio(1);
#pragma unroll
        for (int kk = 0; kk < 2; ++kk)
#pragma unroll
            for (int c = 0; c < 2; ++c)
#pragma unroll
                for (int nt = 0; nt < 4; ++nt)
                    sb[c][nt] = __builtin_amdgcn_mfma_f32_16x16x32_bf16(kfb[c][kk], qf[nt][kk], sb[c][nt], 0, 0, 0);
        __builtin_amdgcn_s_setprio(0);

        // --- half0: exp + in-register pack + PV + MFMA-lsum (no LDS) ---
        {
            bf16x8 bp[4];
#pragma unroll
            for (int nt = 0; nt < 4; ++nt) {
                float p0 = __builtin_amdgcn_exp2f(sa[0][nt][0]);
                float p1 = __builtin_amdgcn_exp2f(sa[0][nt][1]);
                float p2 = __builtin_amdgcn_exp2f(sa[0][nt][2]);
                float p3 = __builtin_amdgcn_exp2f(sa[0][nt][3]);
                float p4 = __builtin_amdgcn_exp2f(sa[1][nt][0]);
                float p5 = __builtin_amdgcn_exp2f(sa[1][nt][1]);
                float p6 = __builtin_amdgcn_exp2f(sa[1][nt][2]);
                float p7 = __builtin_amdgcn_exp2f(sa[1][nt][3]);
                bf16x8 pk = {(bf16_t)p0, (bf16_t)p1, (bf16_t)p2, (bf16_t)p3,
                             (bf16_t)p4, (bf16_t)p5, (bf16_t)p6, (bf16_t)p7};
                bp[nt] = pk;
            }
            __builtin_amdgcn_s_setprio(1);
#pragma unroll
            for (int dt = 0; dt < 4; ++dt)
#pragma unroll
                for (int nt = 0; nt < 4; ++nt)
                    oacc[dt][nt] = __builtin_amdgcn_mfma_f32_16x16x32_bf16(vfa[dt], bp[nt], oacc[dt][nt], 0, 0, 0);
#pragma unroll
            for (int nt = 0; nt < 4; ++nt)
                lacc[nt] = __builtin_amdgcn_mfma_f32_16x16x32_bf16(vone, bp[nt], lacc[nt], 0, 0, 0);
            __builtin_amdgcn_s_setprio(0);
        }

        // --- half1: exp + in-register pack + PV + MFMA-lsum (no LDS) ---
        {
            bf16x8 bp[4];
#pragma unroll
            for (int nt = 0; nt < 4; ++nt) {
                float p0 = __builtin_amdgcn_exp2f(sb[0][nt][0]);
                float p1 = __builtin_amdgcn_exp2f(sb[0][nt][1]);
                float p2 = __builtin_amdgcn_exp2f(sb[0][nt][2]);
                float p3 = __builtin_amdgcn_exp2f(sb[0][nt][3]);
                float p4 = __builtin_amdgcn_exp2f(sb[1][nt][0]);
                float p5 = __builtin_amdgcn_exp2f(sb[1][nt][1]);
                float p6 = __builtin_amdgcn_exp2f(sb[1][nt][2]);
                float p7 = __builtin_amdgcn_exp2f(sb[1][nt][3]);
                bf16x8 pk = {(bf16_t)p0, (bf16_t)p1, (bf16_t)p2, (bf16_t)p3,
                             (bf16_t)p4, (bf16_t)p5, (bf16_t)p6, (bf16_t)p7};
                bp[nt] = pk;
            }
            __builtin_amdgcn_s_setprio(1);
#pragma unroll
            for (int dt = 0; dt < 4; ++dt)
#pragma unroll
                for (int nt = 0; nt < 4; ++nt)
                    oacc[dt][nt] = __builtin_amdgcn_mfma_f32_16x16x32_bf16(vfb[dt], bp[nt], oacc[dt][nt], 0, 0, 0);
#pragma unroll
            for (int nt = 0; nt < 4; ++nt)
                lacc[nt] = __builtin_amdgcn_mfma_f32_16x16x32_bf16(vone, bp[nt], lacc[nt], 0, 0, 0);
            __builtin_amdgcn_s_setprio(0);
        }
    }

    // lacc[nt][0] (any reg — all C/D rows identical) = full per-q sum for this
    // wave's 512 keys; no cross-g shfl needed. Cross-wave merge stays via Lbuf.

    // 4-partial merge through LDS, 4 phases (one 16-col d-chunk each, keeps LDS at 24 KB)
    float linv = 0.f;
#pragma unroll
    for (int p = 0; p < 4; ++p) {
        __syncthreads();
#pragma unroll
        for (int nt = 0; nt < 4; ++nt)
            *(floatx4*)&Mbuf[w * 1280 + (nt * 16 + lm) * 20 + g * 4] = oacc[p][nt];
        if (p == 0 && g == 0)
#pragma unroll
            for (int nt = 0; nt < 4; ++nt)
                Lbuf[w * 64 + nt * 16 + lm] = lacc[nt][0];
        __syncthreads();
        if (p == 0) {
            float lt = 0.f;
#pragma unroll
            for (int w2 = 0; w2 < 4; ++w2)
                lt += Lbuf[w2 * 64 + w * 16 + lm];
            linv = 1.0f / lt;
        }
        {
            floatx4 s = {0.f, 0.f, 0.f, 0.f};
#pragma unroll
            for (int w2 = 0; w2 < 4; ++w2)
                s += *(const floatx4*)&Mbuf[w2 * 1280 + (w * 16 + lm) * 20 + g * 4];
            bf16x4 pk = {(bf16_t)(s[0] * linv), (bf16_t)(s[1] * linv),
                         (bf16_t)(s[2] * linv), (bf16_t)(s[3] * linv)};
            *(bf16x4*)&Ct[w * 384 + lm * 24 + g * 4] = pk;
        }
        // cooperative row store: 8B/lane, 32B per row
        {
            int row = l >> 2, dp = l & 3;
            bf16x4 v = *(const bf16x4*)&Ct[w * 384 + row * 24 + dp * 4];
            *(bf16x4*)&Cc[((size_t)(b * SEQ + q0 + w * 16 + row)) * DMODEL + h * DKH + p * 16 + dp * 4] = v;
        }
    }
}

// ----------------------------------------------------------------------------
extern "C" void kernel_launch(void* const* d_in, const int* in_sizes, int n_in,
                              void* d_out, int out_size, void* d_ws, size_t ws_size,
                              hipStream_t stream) {
    const float* x  = (const float*)d_in[0];
    const float* Wq = (const float*)d_in[1];
    const float* Wk = (const float*)d_in[2];
    const float* Wv = (const float*)d_in[3];
    const float* Wo = (const float*)d_in[4];

    const size_t NX = (size_t)MROWS * DMODEL;
    const size_t NW = (size_t)DMODEL * DMODEL;
    bf16_t* ws  = (bf16_t*)d_ws;
    bf16_t* xb  = ws;            // x bf16
    bf16_t* Wt  = xb + NX;       // W^T x4 contiguous: q,k,v,o
    bf16_t* Wto = Wt + 3 * NW;
    bf16_t* Qfb = Wt + 4 * NW;   // Q frag-major (B-operand), scaled log2(e)/8
    bf16_t* Kfb = Qfb + NX;      // K frag-major (key-permuted A-operand)
    bf16_t* Vfb = Kfb + NX;      // V frag-major
    bf16_t* Cc  = Vfb + NX;      // concat

    prep_kernel<<<dim3(32, 32, 5), dim3(32, 8), 0, stream>>>(x, Wq, Wk, Wv, Wo, xb, Wt);

    gemm_qkv_kernel<<<dim3(12, 16), 512, 131072, stream>>>(xb, Wt, Qfb, Kfb, Vfb);

    // R9: bh on X (R3 mapping) — same-bh blocks stride-32 in linear ID -> one XCD
    attn_kernel<<<dim3(BATCH * NHEADS, SEQ / 64), 256, 0, stream>>>(Qfb, Kfb, Vfb, Cc);

    gemmO_kernel<<<dim3(DMODEL / 128, MROWS / 64), 256, 0, stream>>>(Cc, Wto, (float*)d_out);
}